// Round 1
// baseline (435.448 us; speedup 1.0000x reference)
//
#include <hip/hip_runtime.h>

typedef __bf16 bf16;
typedef bf16 bf16x4 __attribute__((ext_vector_type(4)));
typedef bf16 bf16x8 __attribute__((ext_vector_type(8)));
typedef float f32x4 __attribute__((ext_vector_type(4)));

#define D_MODEL 1024
#define NHEAD   16
#define D_K     64
#define BATCH   8
#define SEQL    1024
#define MROWS   (BATCH*SEQL)   // 8192

// ---------------- f32 -> bf16 conversion (7 arrays in one launch) ----------------
struct Cvt7 {
    const float* s[7];
    bf16*        d[7];
    int          n[7];
};

__global__ __launch_bounds__(256) void cvt7_kernel(Cvt7 a) {
    const int y = blockIdx.y;
    const float* __restrict__ src = a.s[y];
    bf16* __restrict__ dst = a.d[y];
    const int n4 = a.n[y] >> 2;
    const int stride = gridDim.x * blockDim.x;
    for (int i = blockIdx.x * blockDim.x + threadIdx.x; i < n4; i += stride) {
        float4 v = ((const float4*)src)[i];
        bf16x4 o = { (bf16)v.x, (bf16)v.y, (bf16)v.z, (bf16)v.w };
        ((bf16x4*)dst)[i] = o;
    }
}

// ---------------- GEMM core: C = A * B^T, A[M,K] bf16 row-major, B[N,K] bf16 row-major ----------------
// m97 structure: 128x128 tile, BK=32, 4 waves (2x2 of 64x64), global_load_lds w=16.
#define BM 128
#define BN 128
#define BK 32

__device__ __forceinline__ void gemm_core(const bf16* __restrict__ A, const bf16* __restrict__ B,
                                          int bm, int bn, int K,
                                          bf16* lA, bf16* lB, f32x4 (&acc)[4][4]) {
    const int t = threadIdx.x;
    const int lane = t & 63, w = t >> 6;
    const int wr = w >> 1, wc = w & 1;
    const int r = lane & 15, kb = lane >> 4;

    for (int k0 = 0; k0 < K; k0 += BK) {
        __syncthreads();   // previous iteration's ds_reads done before overwrite
        #pragma unroll
        for (int i = 0; i < 2; ++i) {
            const int off = i * 4096 + w * 1024 + lane * 16;   // byte offset in 8 KiB tile
            const int row = off >> 6;                          // tile row (64 B per row)
            const int cb  = off & 63;                          // byte within row
            const bf16* srcA = A + (size_t)(bm + row) * K + k0 + (cb >> 1);
            const bf16* srcB = B + (size_t)(bn + row) * K + k0 + (cb >> 1);
            __builtin_amdgcn_global_load_lds(
                (const __attribute__((address_space(1))) unsigned int*)srcA,
                (__attribute__((address_space(3))) unsigned int*)((char*)lA + i * 4096 + w * 1024),
                16, 0, 0);
            __builtin_amdgcn_global_load_lds(
                (const __attribute__((address_space(1))) unsigned int*)srcB,
                (__attribute__((address_space(3))) unsigned int*)((char*)lB + i * 4096 + w * 1024),
                16, 0, 0);
        }
        __syncthreads();   // staging visible (vmcnt drain)

        bf16x8 af[4], bfr[4];
        #pragma unroll
        for (int m = 0; m < 4; ++m)
            af[m] = *(const bf16x8*)(lA + (wr * 64 + m * 16 + r) * BK + kb * 8);
        #pragma unroll
        for (int n = 0; n < 4; ++n)
            bfr[n] = *(const bf16x8*)(lB + (wc * 64 + n * 16 + r) * BK + kb * 8);
        #pragma unroll
        for (int m = 0; m < 4; ++m)
            #pragma unroll
            for (int n = 0; n < 4; ++n)
                acc[m][n] = __builtin_amdgcn_mfma_f32_16x16x32_bf16(af[m], bfr[n], acc[m][n], 0, 0, 0);
    }
}

// ---------------- Q/K/V projections (one launch, z = 0/1/2) ----------------
// z=0: Q -> Qp[b,h,s,d]   z=1: K -> Kp[b,h,s,d]   z=2: V -> Vt[b,h,d,s] (transposed for PV MFMA)
__global__ __launch_bounds__(256) void proj3_kernel(
        const bf16* __restrict__ xq, const bf16* __restrict__ xk, const bf16* __restrict__ xv,
        const bf16* __restrict__ Wqb, const bf16* __restrict__ Wkb, const bf16* __restrict__ Wvb,
        const float* __restrict__ bq, const float* __restrict__ bk, const float* __restrict__ bv,
        bf16* __restrict__ Qp, bf16* __restrict__ Kp, bf16* __restrict__ Vt) {
    __shared__ bf16 lA[BM * BK], lB[BN * BK];
    const int z = blockIdx.z;
    const bf16* A    = (z == 0) ? xq  : (z == 1) ? xk  : xv;
    const bf16* Bm   = (z == 0) ? Wqb : (z == 1) ? Wkb : Wvb;
    const float* bias = (z == 0) ? bq : (z == 1) ? bk  : bv;
    const int bm = blockIdx.x * BM, bn = blockIdx.y * BN;

    f32x4 acc[4][4] = {};
    gemm_core(A, Bm, bm, bn, D_MODEL, lA, lB, acc);

    const int lane = threadIdx.x & 63, w = threadIdx.x >> 6;
    const int wr = w >> 1, wc = w & 1, r = lane & 15, g = lane >> 4;
    #pragma unroll
    for (int n = 0; n < 4; ++n) {
        const int col = bn + wc * 64 + n * 16 + r;      // output feature
        const float bvl = bias[col];
        const int h = col >> 6, d = col & 63;
        #pragma unroll
        for (int m = 0; m < 4; ++m) {
            #pragma unroll
            for (int j = 0; j < 4; ++j) {
                const int row = bm + wr * 64 + m * 16 + g * 4 + j;   // token index
                const float v = acc[m][n][j] + bvl;
                const int b = row >> 10, s = row & (SEQL - 1);
                const int bh = b * NHEAD + h;
                if (z == 0) {
                    Qp[((size_t)bh * SEQL + s) * D_K + d] = (bf16)v;
                } else if (z == 1) {
                    Kp[((size_t)bh * SEQL + s) * D_K + d] = (bf16)v;
                } else {
                    Vt[((size_t)bh * D_K + d) * SEQL + s] = (bf16)v;
                }
            }
        }
    }
}

// ---------------- output projection: out = AO * Wo^T + bo (f32 out) ----------------
__global__ __launch_bounds__(256) void outproj_kernel(
        const bf16* __restrict__ AO, const bf16* __restrict__ Wob,
        const float* __restrict__ bo, float* __restrict__ out) {
    __shared__ bf16 lA[BM * BK], lB[BN * BK];
    const int bm = blockIdx.x * BM, bn = blockIdx.y * BN;
    f32x4 acc[4][4] = {};
    gemm_core(AO, Wob, bm, bn, D_MODEL, lA, lB, acc);

    const int lane = threadIdx.x & 63, w = threadIdx.x >> 6;
    const int wr = w >> 1, wc = w & 1, r = lane & 15, g = lane >> 4;
    #pragma unroll
    for (int n = 0; n < 4; ++n) {
        const int col = bn + wc * 64 + n * 16 + r;
        const float bvl = bo[col];
        #pragma unroll
        for (int m = 0; m < 4; ++m)
            #pragma unroll
            for (int j = 0; j < 4; ++j) {
                const int row = bm + wr * 64 + m * 16 + g * 4 + j;
                out[(size_t)row * D_MODEL + col] = acc[m][n][j] + bvl;
            }
    }
}

// ---------------- fused masked flash attention ----------------
// grid: (S/64, B*H). Block = 4 waves; wave w owns 16 q-rows. KV tiles of 64.
// Per wave, per KV tile: 8 MFMA QK^T + mask + online softmax + P->LDS (XOR-swizzled) + 8 MFMA PV.
__global__ __launch_bounds__(256) void attn_kernel(
        const bf16* __restrict__ Qp, const bf16* __restrict__ Kp, const bf16* __restrict__ Vt,
        const unsigned int* __restrict__ mask, bf16* __restrict__ AO) {
    __shared__ bf16 plds[4][16 * 64];    // per-wave P tile (2 KiB each)
    const int bh = blockIdx.y, b = bh >> 4, h = bh & 15;
    const int t = threadIdx.x, lane = t & 63, w = t >> 6;
    const int q0 = blockIdx.x * 64 + w * 16;     // this wave's q-row base
    const int r = lane & 15, g = lane >> 4;

    const bf16* __restrict__ Qh = Qp + ((size_t)bh * SEQL + q0) * D_K;
    const bf16* __restrict__ Kh = Kp + (size_t)bh * SEQL * D_K;
    const bf16* __restrict__ Vh = Vt + (size_t)bh * D_K * SEQL;
    const unsigned int* __restrict__ Mq = mask + ((size_t)bh * SEQL + q0) * SEQL;

    // Q fragments held in registers for the whole pass
    bf16x8 qf[2];
    #pragma unroll
    for (int kk = 0; kk < 2; ++kk)
        qf[kk] = *(const bf16x8*)(Qh + r * D_K + kk * 32 + g * 8);

    f32x4 o[4] = {};
    float mrun[4] = {-1e30f, -1e30f, -1e30f, -1e30f};
    float lrun[4] = {0.f, 0.f, 0.f, 0.f};
    bf16* P = plds[w];

    for (int s0 = 0; s0 < SEQL; s0 += 64) {
        // ---- QK^T: scores for 16 q x 64 kv ----
        f32x4 sf[4] = {};
        #pragma unroll
        for (int n = 0; n < 4; ++n) {
            #pragma unroll
            for (int kk = 0; kk < 2; ++kk) {
                bf16x8 kf = *(const bf16x8*)(Kh + (size_t)(s0 + n * 16 + r) * D_K + kk * 32 + g * 8);
                sf[n] = __builtin_amdgcn_mfma_f32_16x16x32_bf16(qf[kk], kf, sf[n], 0, 0, 0);
            }
        }
        // ---- mask + scale (lane holds rows q=g*4+j, col kv=n*16+r) ----
        #pragma unroll
        for (int n = 0; n < 4; ++n)
            #pragma unroll
            for (int j = 0; j < 4; ++j) {
                const unsigned mv = Mq[(size_t)(g * 4 + j) * SEQL + s0 + n * 16 + r];
                sf[n][j] = mv ? sf[n][j] * 0.125f : -1e30f;
            }
        // ---- online softmax (row reduce over 16 lanes) ----
        float rsc[4];
        #pragma unroll
        for (int j = 0; j < 4; ++j) {
            float mx = fmaxf(fmaxf(sf[0][j], sf[1][j]), fmaxf(sf[2][j], sf[3][j]));
            #pragma unroll
            for (int dd = 1; dd < 16; dd <<= 1)
                mx = fmaxf(mx, __shfl_xor(mx, dd));
            const float mn = fmaxf(mrun[j], mx);
            rsc[j] = __expf(mrun[j] - mn);
            mrun[j] = mn;
        }
        float ps[4] = {0.f, 0.f, 0.f, 0.f};
        #pragma unroll
        for (int n = 0; n < 4; ++n)
            #pragma unroll
            for (int j = 0; j < 4; ++j) {
                const float p = __expf(sf[n][j] - mrun[j]);
                sf[n][j] = p;
                ps[j] += p;
            }
        #pragma unroll
        for (int j = 0; j < 4; ++j) {
            #pragma unroll
            for (int dd = 1; dd < 16; dd <<= 1)
                ps[j] += __shfl_xor(ps[j], dd);
            lrun[j] = lrun[j] * rsc[j] + ps[j];
        }
        #pragma unroll
        for (int n = 0; n < 4; ++n)
            #pragma unroll
            for (int j = 0; j < 4; ++j)
                o[n][j] *= rsc[j];
        // ---- P -> LDS (XOR swizzle kills the 128B-row-stride bank conflict) ----
        #pragma unroll
        for (int n = 0; n < 4; ++n)
            #pragma unroll
            for (int j = 0; j < 4; ++j) {
                const int q = g * 4 + j, kv = n * 16 + r;
                const int byteoff = (q * 128 + kv * 2) ^ ((q & 7) << 4);
                *(bf16*)((char*)P + byteoff) = (bf16)sf[n][j];
            }
        asm volatile("s_waitcnt lgkmcnt(0)" ::: "memory");
        __builtin_amdgcn_sched_barrier(0);
        // ---- PV: o[16q][64d] += P[16q][64kv] * V[64kv][64d] ----
        #pragma unroll
        for (int kk = 0; kk < 2; ++kk) {
            const int byteoff = (r * 128 + (kk * 32 + g * 8) * 2) ^ ((r & 7) << 4);
            bf16x8 pf = *(const bf16x8*)((char*)P + byteoff);
            #pragma unroll
            for (int n = 0; n < 4; ++n) {
                bf16x8 vf = *(const bf16x8*)(Vh + (size_t)(n * 16 + r) * SEQL + s0 + kk * 32 + g * 8);
                o[n] = __builtin_amdgcn_mfma_f32_16x16x32_bf16(pf, vf, o[n], 0, 0, 0);
            }
        }
    }
    // ---- epilogue: normalize, write AO[b, s, h*64+d] as bf16 ----
    #pragma unroll
    for (int j = 0; j < 4; ++j) {
        const float inv = 1.0f / lrun[j];
        const int q = q0 + g * 4 + j;
        #pragma unroll
        for (int n = 0; n < 4; ++n) {
            const int d = n * 16 + r;
            AO[((size_t)(b * SEQL + q)) * D_MODEL + h * D_K + d] = (bf16)(o[n][j] * inv);
        }
    }
}

// ---------------- launch ----------------
extern "C" void kernel_launch(void* const* d_in, const int* in_sizes, int n_in,
                              void* d_out, int out_size, void* d_ws, size_t ws_size,
                              hipStream_t stream) {
    const float* q    = (const float*)d_in[0];
    const float* k    = (const float*)d_in[1];
    const float* v    = (const float*)d_in[2];
    const unsigned int* mask = (const unsigned int*)d_in[3];
    const float* Wq = (const float*)d_in[4];
    const float* bq = (const float*)d_in[5];
    const float* Wk = (const float*)d_in[6];
    const float* bk = (const float*)d_in[7];
    const float* Wv = (const float*)d_in[8];
    const float* bv = (const float*)d_in[9];
    const float* Wo = (const float*)d_in[10];
    const float* bo = (const float*)d_in[11];

    char* ws = (char*)d_ws;
    const size_t MB = 1u << 20;
    bf16* qb  = (bf16*)(ws + 0 * MB);
    bf16* kb  = (bf16*)(ws + 16 * MB);
    bf16* vb  = (bf16*)(ws + 32 * MB);
    bf16* Wqb = (bf16*)(ws + 48 * MB);
    bf16* Wkb = (bf16*)(ws + 50 * MB);
    bf16* Wvb = (bf16*)(ws + 52 * MB);
    bf16* Wob = (bf16*)(ws + 54 * MB);
    bf16* Qp  = (bf16*)(ws + 56 * MB);
    bf16* Kp  = (bf16*)(ws + 72 * MB);
    bf16* Vt  = (bf16*)(ws + 88 * MB);
    bf16* AO  = (bf16*)(ws + 104 * MB);   // needs 120 MiB total

    Cvt7 c;
    c.s[0] = q;  c.d[0] = qb;  c.n[0] = MROWS * D_MODEL;
    c.s[1] = k;  c.d[1] = kb;  c.n[1] = MROWS * D_MODEL;
    c.s[2] = v;  c.d[2] = vb;  c.n[2] = MROWS * D_MODEL;
    c.s[3] = Wq; c.d[3] = Wqb; c.n[3] = D_MODEL * D_MODEL;
    c.s[4] = Wk; c.d[4] = Wkb; c.n[4] = D_MODEL * D_MODEL;
    c.s[5] = Wv; c.d[5] = Wvb; c.n[5] = D_MODEL * D_MODEL;
    c.s[6] = Wo; c.d[6] = Wob; c.n[6] = D_MODEL * D_MODEL;
    cvt7_kernel<<<dim3(1024, 7), 256, 0, stream>>>(c);

    proj3_kernel<<<dim3(MROWS / BM, D_MODEL / BN, 3), 256, 0, stream>>>(
        qb, kb, vb, Wqb, Wkb, Wvb, bq, bk, bv, Qp, Kp, Vt);

    attn_kernel<<<dim3(SEQL / 64, BATCH * NHEAD), 256, 0, stream>>>(Qp, Kp, Vt, mask, AO);

    outproj_kernel<<<dim3(MROWS / BM, D_MODEL / BN), 256, 0, stream>>>(AO, Wob, bo, (float*)d_out);
}